// Round 6
// baseline (401.887 us; speedup 1.0000x reference)
//
#include <hip/hip_runtime.h>
#include <stdint.h>

#define SCALE 0.25f
#define OUT_H 7
#define OUT_W 7
#define CV 256
#define HV 200
#define WV 200
#define CPB 64               // channels per block (gridDim.y = CV/CPB)
#define CPW 16               // channels per wave (4 waves/block)
#define MAXROWS 14
#define MAXSPANP 208         // max padded span (span<=200, padded to mult of 16)
#define TPB 256

struct XSide { int xb; float wA, wB; };
struct YSide { int y0c, y1c; float wA, wB; };

__device__ __forceinline__ XSide xside(float sx, float tx, int ow) {
    const float xs = (2.0f * (float)ow + 1.0f) / (float)OUT_W - 1.0f;
    const float gx = sx * xs + tx;
    const float px = ((gx + 1.0f) * (float)WV - 1.0f) * 0.5f;
    const float x0f = floorf(px);
    const float wx1 = px - x0f, wx0 = 1.0f - wx1;
    const int x0i = (int)x0f, x1i = x0i + 1;
    const bool vx0 = (x0i >= 0 && x0i < WV);
    const bool vx1 = (x1i >= 0 && x1i < WV);
    XSide r;
    r.xb = min(max(x0i, 0), WV - 2);
    r.wA = (vx0 && x0i == r.xb)     ? wx0 : ((vx1 && x1i == r.xb)     ? wx1 : 0.0f);
    r.wB = (vx1 && x1i == r.xb + 1) ? wx1 : ((vx0 && x0i == r.xb + 1) ? wx0 : 0.0f);
    return r;
}

__device__ __forceinline__ YSide yside(float sy, float ty, int oh) {
    const float ys = (2.0f * (float)oh + 1.0f) / (float)OUT_H - 1.0f;
    const float gy = sy * ys + ty;
    const float py = ((gy + 1.0f) * (float)HV - 1.0f) * 0.5f;
    const float y0f = floorf(py);
    const float wy1 = py - y0f, wy0 = 1.0f - wy1;
    const int y0i = (int)y0f, y1i = y0i + 1;
    YSide r;
    r.wA = (y0i >= 0 && y0i < HV) ? wy0 : 0.0f;
    r.wB = (y1i >= 0 && y1i < HV) ? wy1 : 0.0f;
    r.y0c = min(max(y0i, 0), HV - 1);
    r.y1c = min(max(y1i, 0), HV - 1);
    return r;
}

__global__ __launch_bounds__(TPB) void roi_align_kernel(
    const float* __restrict__ fm, const float* __restrict__ rois,
    float* __restrict__ out)
{
    __shared__ float  s_buf[4][MAXROWS * MAXSPANP];   // per-wave staging buffers
    __shared__ float4 s_w[49];
    __shared__ int s_slot0[7], s_slot1[7], s_dx[7], s_rowy[MAXROWS];
    __shared__ int s_b, s_xlo, s_span, s_spanp, s_nrows;

    const int n = blockIdx.x;
    const int q = blockIdx.y;
    const int tid = threadIdx.x;

    if (tid < 49) {
        const float r0 = rois[n * 5 + 0] * SCALE;
        const float r1 = rois[n * 5 + 1] * SCALE;
        const float r2 = rois[n * 5 + 2] * SCALE;
        const float r3 = rois[n * 5 + 3] * SCALE;
        const float c0 = r0 * SCALE, c1 = r1 * SCALE;   // second scale (faithful)
        const float c2 = r2 * SCALE, c3 = r3 * SCALE;

        const float x_min = fminf(fmaxf(c0, 0.0f), (float)(WV - 1));
        const float y_min = fminf(fmaxf(c1, 0.0f), (float)(HV - 1));
        const float x_max = fminf(fmaxf(c2, x_min + 1.0f), (float)WV);
        const float y_max = fminf(fmaxf(c3, y_min + 1.0f), (float)HV);

        const float sx = x_max - x_min, tx = 2.0f * x_min / (float)WV - 1.0f;
        const float sy = y_max - y_min, ty = 2.0f * y_min / (float)HV - 1.0f;

        const int oh = tid / 7;
        const int ow = tid - oh * 7;

        const XSide X  = xside(sx, tx, ow);
        const XSide X0 = xside(sx, tx, 0);
        const XSide X6 = xside(sx, tx, 6);
        const YSide Y  = yside(sy, ty, oh);
        const YSide Y0 = yside(sy, ty, 0);
        const YSide Y6 = yside(sy, ty, 6);

        const int ylo = Y0.y0c, yhi = Y6.y1c;     // monotone in oh -> covers all rows
        const int R = yhi - ylo + 1;
        const int xlo = X0.xb;                    // monotone in ow
        const bool contig = (R <= MAXROWS);       // contiguous row range fits -> dedup'd load

        s_w[tid] = make_float4(Y.wA * X.wA, Y.wA * X.wB, Y.wB * X.wA, Y.wB * X.wB);

        if (ow == 0) {
            if (contig) { s_slot0[oh] = Y.y0c - ylo; s_slot1[oh] = Y.y1c - ylo; }
            else        { s_slot0[oh] = 2 * oh;      s_slot1[oh] = 2 * oh + 1;
                          s_rowy[2 * oh] = Y.y0c;    s_rowy[2 * oh + 1] = Y.y1c; }
        }
        if (contig && tid < R) s_rowy[tid] = ylo + tid;
        if (oh == 0) s_dx[ow] = X.xb - xlo;
        if (tid == 0) {
            s_b = (int)(rois[n * 5 + 4] * SCALE);  // faithful quirk
            s_xlo = xlo;
            s_span = X6.xb + 2 - xlo;              // [xlo .. X6.xb+1] inclusive
            s_spanp = (s_span + 15) & ~15;
            s_nrows = contig ? R : MAXROWS;
        }
    }
    __syncthreads();

    const int wv = tid >> 6, lane = tid & 63;
    float* buf = s_buf[wv];
    const int b = s_b, xlo = s_xlo, span = s_span, spanp = s_spanp, nrows = s_nrows;

    // loop-invariant per-lane compute state
    int ra0 = 0, ra1 = 0;
    float4 w4 = make_float4(0.f, 0.f, 0.f, 0.f);
    if (lane < 49) {
        const int oh = lane / 7, ow = lane - oh * 7;
        const int dx = s_dx[ow];
        ra0 = s_slot0[oh] * spanp + dx;
        ra1 = s_slot1[oh] * spanp + dx;
        w4 = s_w[lane];
    }

    const int ch0 = q * CPB + wv * CPW;
    for (int i = 0; i < CPW; ++i) {
        const int ch = ch0 + i;
        const float* __restrict__ chbase = fm + ((size_t)b * CV + ch) * (HV * WV) + xlo;

        // stage: async coalesced row loads, all in flight
        for (int s = 0; s < nrows; ++s) {
            const float* __restrict__ rp = chbase + s_rowy[s] * WV;
            float* lp = buf + s * spanp;
            for (int x0 = 0; x0 < span; x0 += 64) {
                const int x = x0 + lane;
                if (x < span) {
                    __builtin_amdgcn_global_load_lds(
                        (const __attribute__((address_space(1))) void*)(rp + x),
                        (__attribute__((address_space(3))) void*)(lp + x0),
                        4, 0, 0);
                }
            }
        }
        asm volatile("s_waitcnt vmcnt(0)" ::: "memory");

        if (lane < 49) {
            const float a00 = buf[ra0], a01 = buf[ra0 + 1];
            const float a10 = buf[ra1], a11 = buf[ra1 + 1];
            float v = w4.x * a00;
            v = fmaf(w4.y, a01, v);
            v = fmaf(w4.z, a10, v);
            v = fmaf(w4.w, a11, v);
            __builtin_nontemporal_store(v, out + ((size_t)n * CV + ch) * 49 + lane);
        }
        // drain LDS reads before next channel's loads overwrite the buffer
        asm volatile("s_waitcnt lgkmcnt(0)" ::: "memory");
    }
}

extern "C" void kernel_launch(void* const* d_in, const int* in_sizes, int n_in,
                              void* d_out, int out_size, void* d_ws, size_t ws_size,
                              hipStream_t stream) {
    const float* fm = (const float*)d_in[0];
    const float* rois = (const float*)d_in[1];
    float* out = (float*)d_out;
    const int N = in_sizes[1] / 5;  // 1000 rois
    roi_align_kernel<<<dim3(N, CV / CPB), dim3(TPB), 0, stream>>>(fm, rois, out);
}

// Round 7
// 37.535 us; speedup vs baseline: 10.7071x; 10.7071x over previous
//
#include <hip/hip_runtime.h>

#define SCALE 0.25f
#define OUT_H 7
#define OUT_W 7
#define CV 256
#define HV 200
#define WV 200
#define CPB 64               // channels per block (gridDim.y = CV/CPB)
#define EPB (CPB * 49)       // 3136 elements per block
#define TPB 448              // 7 waves; 3136 = 448 * 7 exactly
#define ITERS 7

struct f2u { float x, y; };

__global__ __launch_bounds__(TPB) void roi_align_kernel(
    const float* __restrict__ fm, const float* __restrict__ rois,
    float* __restrict__ out)
{
    __shared__ int s_b;
    __shared__ int2   s_o[49];   // linear offsets of (row0,xb), (row1,xb)
    __shared__ float4 s_q[49];   // weights for {r0.x, r0.y, r1.x, r1.y}

    const int n = blockIdx.x;
    const int q = blockIdx.y;
    const int tid = threadIdx.x;

    if (tid < 49) {
        const float r0 = rois[n * 5 + 0] * SCALE;
        const float r1 = rois[n * 5 + 1] * SCALE;
        const float r2 = rois[n * 5 + 2] * SCALE;
        const float r3 = rois[n * 5 + 3] * SCALE;
        if (tid == 0) s_b = (int)(rois[n * 5 + 4] * SCALE);  // faithful quirk

        const float c0 = r0 * SCALE, c1 = r1 * SCALE;        // second scale (faithful)
        const float c2 = r2 * SCALE, c3 = r3 * SCALE;

        const float x_min = fminf(fmaxf(c0, 0.0f), (float)(WV - 1));
        const float y_min = fminf(fmaxf(c1, 0.0f), (float)(HV - 1));
        const float x_max = fminf(fmaxf(c2, x_min + 1.0f), (float)WV);
        const float y_max = fminf(fmaxf(c3, y_min + 1.0f), (float)HV);

        const float sx = x_max - x_min, tx = 2.0f * x_min / (float)WV - 1.0f;
        const float sy = y_max - y_min, ty = 2.0f * y_min / (float)HV - 1.0f;

        const int oh = tid / 7;
        const int ow = tid - oh * 7;

        // x side: merged adjacent pair {x0, x0+1} based at column xb in [0, W-2]
        const float xs = (2.0f * (float)ow + 1.0f) / (float)OUT_W - 1.0f;
        const float gx = sx * xs + tx;
        const float px = ((gx + 1.0f) * (float)WV - 1.0f) * 0.5f;
        const float x0f = floorf(px);
        const float wx1 = px - x0f, wx0 = 1.0f - wx1;
        const int x0i = (int)x0f, x1i = x0i + 1;
        const bool vx0 = (x0i >= 0 && x0i < WV);
        const bool vx1 = (x1i >= 0 && x1i < WV);
        const int xb = min(max(x0i, 0), WV - 2);
        const float wA = (vx0 && x0i == xb)     ? wx0 : ((vx1 && x1i == xb)     ? wx1 : 0.0f);
        const float wB = (vx1 && x1i == xb + 1) ? wx1 : ((vx0 && x0i == xb + 1) ? wx0 : 0.0f);

        // y side
        const float ys = (2.0f * (float)oh + 1.0f) / (float)OUT_H - 1.0f;
        const float gy = sy * ys + ty;
        const float py = ((gy + 1.0f) * (float)HV - 1.0f) * 0.5f;
        const float y0f = floorf(py);
        const float wy1 = py - y0f, wy0 = 1.0f - wy1;
        const int y0i = (int)y0f, y1i = y0i + 1;
        const float wyA = (y0i >= 0 && y0i < HV) ? wy0 : 0.0f;
        const float wyB = (y1i >= 0 && y1i < HV) ? wy1 : 0.0f;
        const int yc0 = min(max(y0i, 0), HV - 1);
        const int yc1 = min(max(y1i, 0), HV - 1);

        s_o[tid] = make_int2(yc0 * WV + xb, yc1 * WV + xb);
        s_q[tid] = make_float4(wyA * wA, wyA * wB, wyB * wA, wyB * wB);
    }
    __syncthreads();

    const int b = s_b;
    const float* __restrict__ base = fm + ((size_t)b * CV + (size_t)q * CPB) * (HV * WV);
    float* __restrict__ outn = out + ((size_t)n * CV + (size_t)q * CPB) * 49;

    // thread tid owns elements e_k = tid + k*448, k=0..6 (exact cover of 3136)
    // incremental (c,p): stride 448 = 9*49 + 7
    int c = tid / 49;
    int p = tid - c * 49;

    f2u    r0s[ITERS], r1s[ITERS];
    float4 ws[ITERS];

    // phase 1: compute addresses, issue ALL 14 gather loads (max MLP)
    #pragma unroll
    for (int k = 0; k < ITERS; ++k) {
        const int2 o = s_o[p];
        ws[k] = s_q[p];
        const float* __restrict__ bc = base + c * (HV * WV);
        r0s[k] = *reinterpret_cast<const f2u*>(bc + o.x);
        r1s[k] = *reinterpret_cast<const f2u*>(bc + o.y);
        // advance e by 448: p += 7 (mod 49), c += 9 (+1 on wrap)
        const int p2 = p + 7;
        const bool wrap = p2 >= 49;
        p = wrap ? p2 - 49 : p2;
        c += wrap ? 10 : 9;
    }

    // phase 2: consume + store
    #pragma unroll
    for (int k = 0; k < ITERS; ++k) {
        const float4 w = ws[k];
        float v = w.x * r0s[k].x;
        v = fmaf(w.y, r0s[k].y, v);
        v = fmaf(w.z, r1s[k].x, v);
        v = fmaf(w.w, r1s[k].y, v);
        __builtin_nontemporal_store(v, &outn[tid + k * TPB]);
    }
}

extern "C" void kernel_launch(void* const* d_in, const int* in_sizes, int n_in,
                              void* d_out, int out_size, void* d_ws, size_t ws_size,
                              hipStream_t stream) {
    const float* fm = (const float*)d_in[0];
    const float* rois = (const float*)d_in[1];
    float* out = (float*)d_out;
    const int N = in_sizes[1] / 5;  // 1000 rois
    roi_align_kernel<<<dim3(N, CV / CPB), dim3(TPB), 0, stream>>>(fm, rois, out);
}